// Round 9
// baseline (332.114 us; speedup 1.0000x reference)
//
#include <hip/hip_runtime.h>
#include <hip/hip_bf16.h>

#define SEQLEN 4096
#define DMODEL 512
#define NHEADS 8

typedef short short8 __attribute__((ext_vector_type(8)));
typedef float f32x4  __attribute__((ext_vector_type(4)));
typedef float f32x16 __attribute__((ext_vector_type(16)));
typedef int   int2v  __attribute__((ext_vector_type(2)));

__device__ __forceinline__ unsigned short f2bf(float f) {
    union { float f; unsigned u; } v; v.f = f;
    unsigned r = v.u + 0x7fffu + ((v.u >> 16) & 1u);
    return (unsigned short)(r >> 16);
}
__device__ __forceinline__ float bf2f(unsigned short u) {
    union { unsigned u; float f; } v; v.u = (unsigned)u << 16; return v.f;
}
__device__ __forceinline__ float exp2v(float x) {
    float r; asm("v_exp_f32 %0, %1" : "=v"(r) : "v"(x)); return r;
}
__device__ __forceinline__ unsigned cvtpk(float lo, float hi) {
    unsigned r; asm("v_cvt_pk_bf16_f32 %0, %1, %2" : "=v"(r) : "v"(lo), "v"(hi)); return r;
}
__device__ __forceinline__ int2v pl32(int a, int b) {
    return __builtin_amdgcn_permlane32_swap(a, b, false, false);
}
__device__ __forceinline__ void gload16(const void* g, void* l) {
    __builtin_amdgcn_global_load_lds(
        (const __attribute__((address_space(1))) void*)g,
        (__attribute__((address_space(3))) void*)l, 16, 0, 0);
}
__device__ __forceinline__ int nchunks(int qs) { return (4 * qs + 4 + 9) / 10; }

// ---------- prep: x->bf16, 4 weights->bf16 (concat), rope tables ----------
__global__ __launch_bounds__(256)
void prep_kernel(const float* __restrict__ x,
                 const float* __restrict__ Wq, const float* __restrict__ Wk,
                 const float* __restrict__ Wv, const float* __restrict__ Wo,
                 unsigned short* __restrict__ xb, unsigned short* __restrict__ Wcat,
                 float* __restrict__ ct, float* __restrict__ st) {
    const int gid = blockIdx.x, tid = threadIdx.x;
    if (gid < 4096) {
        int i = gid * 1024 + tid * 4;
        float4 v = *reinterpret_cast<const float4*>(x + i);
        ushort4 o; o.x = f2bf(v.x); o.y = f2bf(v.y); o.z = f2bf(v.z); o.w = f2bf(v.w);
        *reinterpret_cast<ushort4*>(xb + i) = o;
    } else if (gid < 5120) {
        int i = (gid - 4096) * 1024 + tid * 4;     // 0..1048575
        int z = i >> 18;
        const float* W = (z == 0) ? Wq : (z == 1) ? Wk : (z == 2) ? Wv : Wo;
        int j = i & 262143;
        float4 v = *reinterpret_cast<const float4*>(W + j);
        ushort4 o; o.x = f2bf(v.x); o.y = f2bf(v.y); o.z = f2bf(v.z); o.w = f2bf(v.w);
        *reinterpret_cast<ushort4*>(Wcat + i) = o;
    } else {
        int idx = (gid - 5120) * 256 + tid;        // 0..131071
        int s = idx >> 5, f = idx & 31;
        float inv = exp2f((float)f * -0.4152410118609203f);  // 10000^(-f/32)
        float a = (float)s * inv;
        ct[idx] = cosf(a); st[idx] = sinf(a);
    }
}

// ---------------- bf16 MFMA GEMM:  Y = A @ W^T + b ----------------
// MODE 0: 128x128 tiles, merged QKV (Q rope-scaled, K rope, V transposed -> Vt).
// MODE 1: 128x64 tiles (512 blocks -> 2/CU), out-proj f32 + bias.
template<int MODE>
__global__ __launch_bounds__(256)
void gemm_kernel(const unsigned short* __restrict__ A,
                 const unsigned short* __restrict__ W,
                 const float* __restrict__ bq,
                 const float* __restrict__ bk,
                 const float* __restrict__ bv,
                 const float* __restrict__ ctab,
                 const float* __restrict__ stab,
                 unsigned short* __restrict__ Qb,
                 unsigned short* __restrict__ Kb,
                 unsigned short* __restrict__ Vt,
                 float* __restrict__ Fout)
{
    constexpr int K = 512;
    constexpr int BN  = (MODE == 0) ? 128 : 64;    // N-tile width
    constexpr int NT  = (MODE == 0) ? 12 : 8;      // N tiles
    constexpr int CPX = (MODE == 0) ? 96 : 64;     // blocks per XCD (grid/8)
    constexpr int NTF = (MODE == 0) ? 4 : 2;       // 16-col frags per wave
    __shared__ __align__(16) unsigned short a_sh[3][128 * 32];
    __shared__ __align__(16) unsigned short b_sh[3][BN * 32];

    const int raw = blockIdx.x;
    const int bid = (raw & 7) * CPX + (raw >> 3);  // bijective XCD swizzle
    const int bm = bid / NT, bn = bid % NT;
    const int tid = threadIdx.x;
    const int w = tid >> 6, l = tid & 63;
    const int g = l >> 4, l15 = l & 15;
    const int wr = w >> 1, wc = w & 1;

    const int sr0 = tid >> 2;
    const int swzc = (tid & 3) ^ ((sr0 >> 1) & 3);
    const unsigned wbase = (unsigned)(tid & 0xC0) * 16;
    const unsigned short* arow = A + (size_t)(bm * 128 + sr0) * K + swzc * 8;
    const unsigned short* brow = W + (size_t)(bn * BN + sr0) * K + swzc * 8;

    f32x4 acc[4][NTF];
    #pragma unroll
    for (int p = 0; p < 4; ++p)
        #pragma unroll
        for (int q = 0; q < NTF; ++q)
            acc[p][q] = (f32x4){0.f, 0.f, 0.f, 0.f};

    auto stage = [&](int buf, int k0) {
        char* ab = (char*)a_sh[buf];
        char* bb2 = (char*)b_sh[buf];
        gload16(arow + k0,                      ab + wbase);
        gload16(arow + (size_t)64 * K + k0,     ab + 4096 + wbase);
        gload16(brow + k0,                      bb2 + wbase);
        if constexpr (MODE == 0)
            gload16(brow + (size_t)64 * K + k0, bb2 + 4096 + wbase);
    };
    auto waitvm = [&]() {
        if constexpr (MODE == 0) asm volatile("s_waitcnt vmcnt(4)" ::: "memory");
        else                     asm volatile("s_waitcnt vmcnt(3)" ::: "memory");
    };

    stage(0, 0);
    stage(1, 32);
    waitvm();
    __builtin_amdgcn_s_barrier();

    int cb = 0;
    for (int ks = 0; ks < 16; ++ks) {
        int pb = cb + 2; if (pb >= 3) pb -= 3;
        stage(pb, (ks + 2 < 16) ? (ks + 2) * 32 : 480);

        const char* ab = (const char*)a_sh[cb];
        const char* bb2 = (const char*)b_sh[cb];
        short8 af[4], bf[NTF];
        #pragma unroll
        for (int mt = 0; mt < 4; ++mt) {
            int r = wr * 64 + mt * 16 + l15;
            int ofs = (r * 64 + g * 16) ^ (((r >> 1) & 3) << 4);
            af[mt] = *reinterpret_cast<const short8*>(ab + ofs);
        }
        #pragma unroll
        for (int nt = 0; nt < NTF; ++nt) {
            int r = wc * (BN / 2) + nt * 16 + l15;
            int ofs = (r * 64 + g * 16) ^ (((r >> 1) & 3) << 4);
            bf[nt] = *reinterpret_cast<const short8*>(bb2 + ofs);
        }
        __builtin_amdgcn_s_setprio(1);
        #pragma unroll
        for (int mt = 0; mt < 4; ++mt)
            #pragma unroll
            for (int nt = 0; nt < NTF; ++nt)
                acc[mt][nt] = __builtin_amdgcn_mfma_f32_16x16x32_bf16(af[mt], bf[nt], acc[mt][nt], 0, 0, 0);
        __builtin_amdgcn_s_setprio(0);

        waitvm();
        __builtin_amdgcn_s_barrier();
        cb = (cb == 2) ? 0 : cb + 1;
    }

    const int m_base = bm * 128 + wr * 64;

    if (MODE == 1) {
        const int n_base = bn * 64 + wc * 32;
        #pragma unroll
        for (int mt = 0; mt < 4; ++mt)
            for (int nt = 0; nt < NTF; ++nt) {
                int n = n_base + nt * 16 + l15;
                float bb = bq[n];
                #pragma unroll
                for (int i = 0; i < 4; ++i) {
                    int m = m_base + mt * 16 + g * 4 + i;
                    Fout[(size_t)m * 512 + n] = acc[mt][nt][i] + bb;
                }
            }
    } else {
        const int z = bn >> 2;                       // 0:Q 1:K 2:V
        const int nc0 = (bn & 3) * 128 + wc * 64;
        const float* bias = (z == 0) ? bq : (z == 1) ? bk : bv;
        if (z < 2) {
            unsigned short* Y = z ? Kb : Qb;
            const float qsc = z ? 1.0f : 0.18033688011112042f;  // 0.125 * log2(e)
            #pragma unroll
            for (int mt = 0; mt < 4; ++mt)
                for (int ntl = 0; ntl < 2; ++ntl) {
                    int hd0 = (ntl * 16 + l15) & 31;
                    int n0 = nc0 + ntl * 16 + l15;
                    float bb0 = bias[n0];
                    float bb1 = bias[n0 + 32];
                    #pragma unroll
                    for (int i = 0; i < 4; ++i) {
                        int m = m_base + mt * 16 + g * 4 + i;
                        int sidx = m & (SEQLEN - 1);
                        float cs = ctab[sidx * 32 + hd0];
                        float sn = stab[sidx * 32 + hd0];
                        float v0 = acc[mt][ntl][i] + bb0;
                        float v1 = acc[mt][ntl + 2][i] + bb1;
                        Y[(size_t)m * 512 + n0]      = f2bf((v0 * cs - v1 * sn) * qsc);
                        Y[(size_t)m * 512 + n0 + 32] = f2bf((v1 * cs + v0 * sn) * qsc);
                    }
                }
        } else if constexpr (MODE == 0) {
            // V: transpose 128x128 tile via LDS (32 KB), store Vt[(b*8+h)*64+d][s]
            asm volatile("s_waitcnt vmcnt(0)" ::: "memory");   // drain pending gload_lds
            __builtin_amdgcn_s_barrier();
            char* T = (char*)a_sh;
            #pragma unroll
            for (int mt = 0; mt < 4; ++mt)
                #pragma unroll
                for (int nt = 0; nt < 4; ++nt) {
                    int nv_l = wc * 64 + nt * 16 + l15;
                    float bb = bias[(bn & 3) * 128 + nv_l];
                    #pragma unroll
                    for (int i = 0; i < 4; i += 2) {
                        int m_l = wr * 64 + mt * 16 + g * 4 + i;
                        unsigned u = cvtpk(acc[mt][nt][i] + bb, acc[mt][nt][i + 1] + bb);
                        int byte0 = nv_l * 256 + ((m_l * 2) ^ ((nv_l & 7) << 4));
                        *reinterpret_cast<unsigned*>(T + byte0) = u;
                    }
                }
            __builtin_amdgcn_s_barrier();
            const int b_out = bm >> 5;
            const int s0 = (bm & 31) * 128;
            #pragma unroll
            for (int p = 0; p < 8; ++p) {
                int nv_l = p * 16 + (tid >> 4);
                int c = tid & 15;
                int byte = nv_l * 256 + ((c * 16) ^ ((nv_l & 7) << 4));
                short8 v = *reinterpret_cast<const short8*>(T + byte);
                int nv_g = (bn & 3) * 128 + nv_l;
                int hg = nv_g >> 6, d = nv_g & 63;
                *reinterpret_cast<short8*>(
                    Vt + ((size_t)((b_out * 8 + hg) * 64 + d)) * SEQLEN + s0 + c * 8) = v;
            }
        }
    }
}

// ---------------- causal flash attention: uniform KV-chunks of <=10 tiles ----------------
// 4 waves x 64 q-rows (dual set). K triple-buffered in LDS (counted vmcnt(2));
// V-fragments loaded DIRECT from global (L1/L2-resident), latency hidden under softmax.
// grid slice via idx_off for profiling visibility. Partials as in round 7/8.
__global__ __launch_bounds__(256, 3)
void attn_kernel(const unsigned short* __restrict__ Qg,
                 const unsigned short* __restrict__ Kg,
                 const unsigned short* __restrict__ Vt,
                 unsigned short* __restrict__ O,
                 unsigned short* __restrict__ Opt,
                 float* __restrict__ Ml,
                 int idx_off)
{
    __shared__ __align__(16) unsigned short k_sh[3][64 * 64];   // 24 KB

    const int bx = blockIdx.x;
    const int bh = bx & 15;
    const int idx = (bx >> 4) + idx_off;           // 0..60, heavy-first
    int qs = 15, accn = 0;
    for (;;) {
        int nb = nchunks(qs);
        if (accn + nb > idx) break;
        accn += nb; --qs;
    }
    const int ck = idx - accn;
    const int HT4 = 4 * qs + 4;
    const int t0 = ck * 10;
    const int t1 = (t0 + 10 < HT4) ? t0 + 10 : HT4;
    const bool single = (HT4 <= 10);
    const int slot = bh * 61 + idx;

    const int b = bh >> 3, hh = bh & 7;
    const int tid = threadIdx.x;
    const int w = tid >> 6, l = tid & 63;
    const int l31 = l & 31, h = l >> 5;

    const size_t qkbase = (size_t)b * SEQLEN * DMODEL + hh * 64;
    const unsigned short* Vrow = Vt + (size_t)bh * 64 * SEQLEN;

    const int r0 = tid >> 3, cb0 = tid & 7;
    const int scs = cb0 ^ (r0 & 7);
    const unsigned short* ksrc0 = Kg + qkbase + (size_t)r0 * DMODEL + scs * 8;
    const unsigned short* vrow0 = Vrow + (size_t)l31 * SEQLEN + h * 8;        // set-row V base
    const unsigned short* vrow1 = Vrow + (size_t)(32 + l31) * SEQLEN + h * 8;

    const int swz = (l31 & 7) << 4;
    const int td = 4 * qs + w;                     // wave's diagonal tile (global index)
    const int tlimit = td + 1;
    const int qg0 = qs * 256 + w * 64 + l31;
    const int qg1 = qg0 + 32;
    const int ql0 = w * 64 + l31;                  // tile-local q rows
    const int ql1 = ql0 + 32;

    short8 qf0[4], qf1[4];
    {
        const unsigned short* qr0 = Qg + qkbase + (size_t)qg0 * DMODEL;
        const unsigned short* qr1 = Qg + qkbase + (size_t)qg1 * DMODEL;
        #pragma unroll
        for (int kk = 0; kk < 4; ++kk) {
            qf0[kk] = *reinterpret_cast<const short8*>(qr0 + kk * 16 + h * 8);
            qf1[kk] = *reinterpret_cast<const short8*>(qr1 + kk * 16 + h * 8);
        }
    }

    f32x16 oa00, oa01, oa10, oa11;
    #pragma unroll
    for (int i = 0; i < 16; ++i) { oa00[i] = 0.f; oa01[i] = 0.f; oa10[i] = 0.f; oa11[i] = 0.f; }
    float m0 = -3.0e38f, l0 = 0.f, m1 = -3.0e38f, l1 = 0.f;

    auto stage = [&](int buf, int t) {
        char* kb = (char*)k_sh[buf];
        const unsigned short* kp = ksrc0 + (size_t)t * 64 * DMODEL;
        gload16(kp,                kb + tid * 16);
        gload16(kp + 32 * DMODEL,  kb + 4096 + tid * 16);
    };

    auto softmax_set = [&](f32x16& sA, f32x16& sB, float& mr, float& lr,
                           f32x16& oaA, f32x16& oaB, short8* pw) {
        float g0 = fmaxf(sA[0], sA[1]);
        g0 = fmaxf(fmaxf(g0, sA[2]), sA[3]);
        g0 = fmaxf(fmaxf(g0, sA[4]), sA[5]);
        g0 = fmaxf(fmaxf(g0, sA[6]), sA[7]);
        float g1 = fmaxf(sA[8], sA[9]);
        g1 = fmaxf(fmaxf(g1, sA[10]), sA[11]);
        g1 = fmaxf(fmaxf(g1, sA[12]), sA[13]);
        g1 = fmaxf(fmaxf(g1, sA[14]), sA[15]);
        float g2 = fmaxf(sB[0], sB[1]);
        g2 = fmaxf(fmaxf(g2, sB[2]), sB[3]);
        g2 = fmaxf(fmaxf(g2, sB[4]), sB[5]);
        g2 = fmaxf(fmaxf(g2, sB[6]), sB[7]);
        float g3 = fmaxf(sB[8], sB[9]);
        g3 = fmaxf(fmaxf(g3, sB[10]), sB[11]);
        g3 = fmaxf(fmaxf(g3, sB[12]), sB[13]);
        g3 = fmaxf(fmaxf(g3, sB[14]), sB[15]);
        float mloc = fmaxf(fmaxf(g0, g1), fmaxf(g2, g3));
        int2v rp2 = pl32(__float_as_int(mloc), __float_as_int(mloc));
        float pm = fmaxf(__int_as_float(rp2[0]), __int_as_float(rp2[1]));
        float mn = mr;
        if (__any(pm > mr + 8.0f)) {
            mn = fmaxf(mr, pm);
            float al = exp2v(mr - mn);
            mr = mn; lr *= al;
            #pragma unroll
            for (int r = 0; r < 16; ++r) { oaA[r] *= al; oaB[r] *= al; }
        }
        #pragma unroll
        for (int r = 0; r < 16; ++r) sA[r] = exp2v(sA[r] - mn);
        #pragma unroll
        for (int r = 0; r < 16; ++r) sB[r] = exp2v(sB[r] - mn);
        float sm[16];
        #pragma unroll
        for (int r = 0; r < 16; ++r) sm[r] = sA[r] + sB[r];
        #pragma unroll
        for (int str = 8; str >= 1; str >>= 1)
            #pragma unroll
            for (int r = 0; r < str; ++r) sm[r] += sm[r + str];
        int2v rs2 = pl32(__float_as_int(sm[0]), __float_as_int(sm[0]));
        lr += __int_as_float(rs2[0]) + __int_as_float(rs2[1]);
        #pragma unroll
        for (int bb = 0; bb < 4; ++bb) {
            const int rb = (bb & 1) * 8;
            const f32x16& s = (bb < 2) ? sA : sB;
            int pk0 = (int)cvtpk(s[rb + 0], s[rb + 1]);
            int pk1 = (int)cvtpk(s[rb + 2], s[rb + 3]);
            int pk2 = (int)cvtpk(s[rb + 4], s[rb + 5]);
            int pk3 = (int)cvtpk(s[rb + 6], s[rb + 7]);
            int2v r02 = pl32(pk0, pk2);
            int2v r13 = pl32(pk1, pk3);
            union { int u[4]; short8 s8; } w_;
            w_.u[0] = r02[0]; w_.u[1] = r13[0]; w_.u[2] = r02[1]; w_.u[3] = r13[1];
            pw[bb] = w_.s8;
        }
    };

    int cb = t0 % 3;
    stage(cb, t0);
    {
        int nb = cb + 1; if (nb >= 3) nb -= 3;
        stage(nb, (t0 + 1 < t1) ? t0 + 1 : t1 - 1);
    }
    asm volatile("s_waitcnt vmcnt(2)" ::: "memory");
    __builtin_amdgcn_s_barrier();

    for (int t = t0; t < t1; ++t) {
        int pb = cb + 2; if (pb >= 3) pb -= 3;
        stage(pb, (t + 2 < t1) ? t + 2 : t1 - 1);

        if (t < tlimit) {
            const char* kb = (const char*)k_sh[cb];

            f32x16 s00, s01, s10, s11;
            #pragma unroll
            for (int i = 0; i < 16; ++i) { s00[i] = 0.f; s01[i] = 0.f; s10[i] = 0.f; s11[i] = 0.f; }
            __builtin_amdgcn_s_setprio(1);
            #pragma unroll
            for (int kk = 0; kk < 4; ++kk) {
                short8 kf0 = *reinterpret_cast<const short8*>(kb + l31 * 128 + ((kk * 32 + h * 16) ^ swz));
                short8 kf1 = *reinterpret_cast<const short8*>(kb + (32 + l31) * 128 + ((kk * 32 + h * 16) ^ swz));
                s00 = __builtin_amdgcn_mfma_f32_32x32x16_bf16(kf0, qf0[kk], s00, 0, 0, 0);
                s01 = __builtin_amdgcn_mfma_f32_32x32x16_bf16(kf1, qf0[kk], s01, 0, 0, 0);
                s10 = __builtin_amdgcn_mfma_f32_32x32x16_bf16(kf0, qf1[kk], s10, 0, 0, 0);
                s11 = __builtin_amdgcn_mfma_f32_32x32x16_bf16(kf1, qf1[kk], s11, 0, 0, 0);
            }
            __builtin_amdgcn_s_setprio(0);

            // ---- V fragments direct from global; latency hides under softmax ----
            short8 vf0[4], vf1[4];
            #pragma unroll
            for (int bb = 0; bb < 4; ++bb) {
                vf0[bb] = *reinterpret_cast<const short8*>(vrow0 + t * 64 + bb * 16);
                vf1[bb] = *reinterpret_cast<const short8*>(vrow1 + t * 64 + bb * 16);
            }

            if (t == td) {
                #pragma unroll
                for (int r = 0; r < 16; ++r) {
                    int rp = (r & 3) + 8 * (r >> 2) + 4 * h;
                    int kv0 = t * 64 + rp;
                    if (kv0 > qg0)      s00[r] = -3.0e38f;
                    if (kv0 + 32 > qg0) s01[r] = -3.0e38f;
                    if (kv0 > qg1)      s10[r] = -3.0e38f;
                    if (kv0 + 32 > qg1) s11[r] = -3.0e38f;
                }
            }

            short8 pw0[4], pw1[4];
            softmax_set(s00, s01, m0, l0, oa00, oa01, pw0);
            softmax_set(s10, s11, m1, l1, oa10, oa11, pw1);

            __builtin_amdgcn_s_setprio(1);
            #pragma unroll
            for (int bb = 0; bb < 4; ++bb) {
                oa00 = __builtin_amdgcn_mfma_f32_32x32x16_bf16(vf0[bb], pw0[bb], oa00, 0, 0, 0);
                oa01 = __builtin_amdgcn_mfma_f32_32x32x16_bf16(vf1[bb], pw0[bb], oa01, 0, 0, 0);
                oa10 = __builtin_amdgcn_mfma_f32_32x32x16_bf16(vf0[bb], pw1[bb], oa10, 0, 0, 0);
                oa11 = __builtin_amdgcn_mfma_f32_32x32x16_bf16(vf1[bb], pw1[bb], oa11, 0, 0, 0);
            }
            __builtin_amdgcn_s_setprio(0);
        }

        asm volatile("s_waitcnt vmcnt(2)" ::: "memory");
        __builtin_amdgcn_s_barrier();
        cb = (cb == 2) ? 0 : cb + 1;
    }

    if (single) {
        float inv0 = 1.0f / l0, inv1 = 1.0f / l1;
        unsigned short* or0 = O + qkbase + (size_t)qg0 * DMODEL;
        unsigned short* or1 = O + qkbase + (size_t)qg1 * DMODEL;
        #pragma unroll
        for (int r = 0; r < 16; r += 2) {
            int d0 = (r & 3) + 8 * (r >> 2) + 4 * h;
            *reinterpret_cast<unsigned*>(or0 + d0)      = cvtpk(oa00[r] * inv0, oa00[r + 1] * inv0);
            *reinterpret_cast<unsigned*>(or0 + 32 + d0) = cvtpk(oa01[r] * inv0, oa01[r + 1] * inv0);
            *reinterpret_cast<unsigned*>(or1 + d0)      = cvtpk(oa10[r] * inv1, oa10[r + 1] * inv1);
            *reinterpret_cast<unsigned*>(or1 + 32 + d0) = cvtpk(oa11[r] * inv1, oa11[r + 1] * inv1);
        }
    } else {
        float* mlb = Ml + (size_t)slot * 512;
        *reinterpret_cast<float2*>(mlb + ql0 * 2) = make_float2(m0, l0);
        *reinterpret_cast<float2*>(mlb + ql1 * 2) = make_float2(m1, l1);
        unsigned short* opb = Opt + (size_t)slot * 16384;
        #pragma unroll
        for (int r = 0; r < 16; r += 2) {
            int d0 = (r & 3) + 8 * (r >> 2) + 4 * h;
            unsigned u;
            u = cvtpk(oa00[r], oa00[r + 1]);
            opb[d0 * 256 + ql0]        = (unsigned short)u;
            opb[(d0 + 1) * 256 + ql0]  = (unsigned short)(u >> 16);
            u = cvtpk(oa01[r], oa01[r + 1]);
            opb[(d0 + 32) * 256 + ql0] = (unsigned short)u;
            opb[(d0 + 33) * 256 + ql0] = (unsigned short)(u >> 16);
            u = cvtpk(oa10[r], oa10[r + 1]);
            opb[d0 * 256 + ql1]        = (unsigned short)u;
            opb[(d0 + 1) * 256 + ql1]  = (unsigned short)(u >> 16);
            u = cvtpk(oa11[r], oa11[r + 1]);
            opb[(d0 + 32) * 256 + ql1] = (unsigned short)u;
            opb[(d0 + 33) * 256 + ql1] = (unsigned short)(u >> 16);
        }
    }
}

// ---------- combine: merge <=7 chunk partials -> bf16 O[b*4096+q][h*64+d] ----------
// grid = 14 qs (2..15) x 16 bh x 4 q-quarters = 896 blocks.
__global__ __launch_bounds__(256)
void combine_kernel(const unsigned short* __restrict__ Opt, const float* __restrict__ Ml,
                    unsigned short* __restrict__ O) {
    __shared__ float a_sh[7][64];
    __shared__ unsigned short o_sh[64][72];
    const int bx = blockIdx.x;
    const int qs = 2 + (bx >> 6);
    const int rem = bx & 63;
    const int bh = rem >> 2, qq = rem & 3;
    const int b = bh >> 3, hh = bh & 7;
    const int tid = threadIdx.x;

    int accn = 0;
    for (int q2 = 15; q2 > qs; --q2) accn += nchunks(q2);
    const int nb = nchunks(qs);
    const int slotbase = bh * 61 + accn;

    if (tid < 64) {
        int q = qq * 64 + tid;
        float m = -3.0e38f;
        for (int c = 0; c < nb; ++c)
            m = fmaxf(m, Ml[(size_t)(slotbase + c) * 512 + q * 2]);
        float denom = 0.f;
        for (int c = 0; c < nb; ++c) {
            float2 ml = *reinterpret_cast<const float2*>(Ml + (size_t)(slotbase + c) * 512 + q * 2);
            float a = exp2v(ml.x - m);
            denom += a * ml.y;
            a_sh[c][tid] = a;
        }
        float inv = 1.0f / denom;
        for (int c = 0; c < nb; ++c) a_sh[c][tid] *= inv;
    }
    __syncthreads();

    const int d = tid >> 2, q4 = (tid & 3) * 16;
    float acc16[16];
    #pragma unroll
    for (int e = 0; e < 16; ++e) acc16[e] = 0.f;
    for (int c = 0; c < nb; ++c) {
        const unsigned short* p = Opt + (size_t)(slotbase + c) * 16384 + d * 256 + qq * 64 + q4;
        short8 v0 = *reinterpret_cast<const short8*>(p);
        short8 v1 = *reinterpret_cast<const short8*>(p + 8);
        #pragma unroll
        for (int e = 0; e < 8; ++e) {
            acc16[e]     += a_sh[c][q4 + e]     * bf2f((unsigned short)v0[e]);
            acc16[8 + e] += a_sh[c][q4 + 8 + e] * bf2f((unsigned short)v1[e]);
        }
    }
    #pragma unroll
    for (int e = 0; e < 16; ++e) o_sh[q4 + e][d] = f2bf(acc16[e]);
    __syncthreads();

    const int qw = tid >> 2, dc = (tid & 3) * 16;
    const int qglob = qs * 256 + qq * 64 + qw;
    unsigned short* orow = O + ((size_t)(b * 4096 + qglob)) * 512 + hh * 64 + dc;
    #pragma unroll
    for (int j = 0; j < 2; ++j) {
        union { ushort4 h4[2]; short8 s8; } u;
        u.h4[0] = *reinterpret_cast<const ushort4*>(&o_sh[qw][dc + j * 8]);
        u.h4[1] = *reinterpret_cast<const ushort4*>(&o_sh[qw][dc + j * 8 + 4]);
        *reinterpret_cast<short8*>(orow + j * 8) = u.s8;
    }
}

// ---------------- launch ----------------
extern "C" void kernel_launch(void* const* d_in, const int* in_sizes, int n_in,
                              void* d_out, int out_size, void* d_ws, size_t ws_size,
                              hipStream_t stream) {
    const float* x  = (const float*)d_in[0];
    // d_in[1] = mask (ignored; causal mask computed analytically)
    const float* Wq = (const float*)d_in[2];
    const float* bq = (const float*)d_in[3];
    const float* Wk = (const float*)d_in[4];
    const float* bk = (const float*)d_in[5];
    const float* Wv = (const float*)d_in[6];
    const float* bv = (const float*)d_in[7];
    const float* Wo = (const float*)d_in[8];
    const float* bo = (const float*)d_in[9];
    float* out = (float*)d_out;

    const int MD = 8192 * 512;
    const int WD = 512 * 512;
    unsigned short* ws  = (unsigned short*)d_ws;
    unsigned short* xb  = ws;
    unsigned short* Qb  = xb + MD;
    unsigned short* Kb  = Qb + MD;
    unsigned short* Vt  = Kb + MD;        // [16*64][4096] transposed V (written by gemm0)
    unsigned short* Ob  = Vt + MD;
    unsigned short* Wcat = Ob + MD;       // Wq,Wk,Wv,Wo concat [2048][512]
    float* ctab = (float*)(Wcat + 4 * WD);
    float* stab = ctab + SEQLEN * 32;
    // chunk partials: 976 slots x (64d x 256q bf16 = 32KB) = 31.98 MB, then Ml 2.0 MB
    unsigned short* Opt = (unsigned short*)((char*)d_ws + 45088768ull);
    float* Ml  = (float*)((char*)d_ws + 45088768ull + 31981568ull);

    prep_kernel<<<5632, 256, 0, stream>>>(x, Wq, Wk, Wv, Wo, xb, Wcat, ctab, stab);

    gemm_kernel<0><<<dim3(64 * 12), 256, 0, stream>>>(
        xb, Wcat, bq, bk, bv, ctab, stab, Qb, Kb, Vt, nullptr);

    // split attn into two dispatches (profiling visibility + same total work)
    attn_kernel<<<dim3(30 * 16), 256, 0, stream>>>(Qb, Kb, Vt, Ob, Opt, Ml, 0);
    attn_kernel<<<dim3(31 * 16), 256, 0, stream>>>(Qb, Kb, Vt, Ob, Opt, Ml, 30);

    combine_kernel<<<dim3(896), 256, 0, stream>>>(Opt, Ml, Ob);

    gemm_kernel<1><<<dim3(64 * 8), 256, 0, stream>>>(
        Ob, Wcat + 3 * WD, bo, nullptr, nullptr, nullptr, nullptr,
        nullptr, nullptr, nullptr, out);
}

// Round 10
// 221.968 us; speedup vs baseline: 1.4962x; 1.4962x over previous
//
#include <hip/hip_runtime.h>
#include <hip/hip_bf16.h>

#define SEQLEN 4096
#define DMODEL 512
#define NHEADS 8

typedef short short8 __attribute__((ext_vector_type(8)));
typedef float f32x4  __attribute__((ext_vector_type(4)));
typedef float f32x16 __attribute__((ext_vector_type(16)));
typedef int   int2v  __attribute__((ext_vector_type(2)));

__device__ __forceinline__ unsigned short f2bf(float f) {
    union { float f; unsigned u; } v; v.f = f;
    unsigned r = v.u + 0x7fffu + ((v.u >> 16) & 1u);
    return (unsigned short)(r >> 16);
}
__device__ __forceinline__ float bf2f(unsigned short u) {
    union { unsigned u; float f; } v; v.u = (unsigned)u << 16; return v.f;
}
__device__ __forceinline__ float exp2v(float x) {
    float r; asm("v_exp_f32 %0, %1" : "=v"(r) : "v"(x)); return r;
}
__device__ __forceinline__ unsigned cvtpk(float lo, float hi) {
    unsigned r; asm("v_cvt_pk_bf16_f32 %0, %1, %2" : "=v"(r) : "v"(lo), "v"(hi)); return r;
}
__device__ __forceinline__ int2v pl32(int a, int b) {
    return __builtin_amdgcn_permlane32_swap(a, b, false, false);
}
__device__ __forceinline__ void gload16(const void* g, void* l) {
    __builtin_amdgcn_global_load_lds(
        (const __attribute__((address_space(1))) void*)g,
        (__attribute__((address_space(3))) void*)l, 16, 0, 0);
}
__device__ __forceinline__ int nchunks(int qs) { return (4 * qs + 4 + 9) / 10; }

// ---------- prep: x->bf16, 4 weights->bf16 (concat), rope tables ----------
__global__ __launch_bounds__(256)
void prep_kernel(const float* __restrict__ x,
                 const float* __restrict__ Wq, const float* __restrict__ Wk,
                 const float* __restrict__ Wv, const float* __restrict__ Wo,
                 unsigned short* __restrict__ xb, unsigned short* __restrict__ Wcat,
                 float* __restrict__ ct, float* __restrict__ st) {
    const int gid = blockIdx.x, tid = threadIdx.x;
    if (gid < 4096) {
        int i = gid * 1024 + tid * 4;
        float4 v = *reinterpret_cast<const float4*>(x + i);
        ushort4 o; o.x = f2bf(v.x); o.y = f2bf(v.y); o.z = f2bf(v.z); o.w = f2bf(v.w);
        *reinterpret_cast<ushort4*>(xb + i) = o;
    } else if (gid < 5120) {
        int i = (gid - 4096) * 1024 + tid * 4;     // 0..1048575
        int z = i >> 18;
        const float* W = (z == 0) ? Wq : (z == 1) ? Wk : (z == 2) ? Wv : Wo;
        int j = i & 262143;
        float4 v = *reinterpret_cast<const float4*>(W + j);
        ushort4 o; o.x = f2bf(v.x); o.y = f2bf(v.y); o.z = f2bf(v.z); o.w = f2bf(v.w);
        *reinterpret_cast<ushort4*>(Wcat + i) = o;
    } else {
        int idx = (gid - 5120) * 256 + tid;        // 0..131071
        int s = idx >> 5, f = idx & 31;
        float inv = exp2f((float)f * -0.4152410118609203f);  // 10000^(-f/32)
        float a = (float)s * inv;
        ct[idx] = cosf(a); st[idx] = sinf(a);
    }
}

// ---------------- bf16 MFMA GEMM:  Y = A @ W^T + b ----------------
// MODE 0: 128x128 tiles, merged QKV (Q rope-scaled, K rope, V transposed -> Vt).
// MODE 1: 128x64 tiles (512 blocks -> 2/CU), out-proj f32 + bias.
template<int MODE>
__global__ __launch_bounds__(256)
void gemm_kernel(const unsigned short* __restrict__ A,
                 const unsigned short* __restrict__ W,
                 const float* __restrict__ bq,
                 const float* __restrict__ bk,
                 const float* __restrict__ bv,
                 const float* __restrict__ ctab,
                 const float* __restrict__ stab,
                 unsigned short* __restrict__ Qb,
                 unsigned short* __restrict__ Kb,
                 unsigned short* __restrict__ Vt,
                 float* __restrict__ Fout)
{
    constexpr int K = 512;
    constexpr int BN  = (MODE == 0) ? 128 : 64;    // N-tile width
    constexpr int NT  = (MODE == 0) ? 12 : 8;      // N tiles
    constexpr int CPX = (MODE == 0) ? 96 : 64;     // blocks per XCD (grid/8)
    constexpr int NTF = (MODE == 0) ? 4 : 2;       // 16-col frags per wave
    __shared__ __align__(16) unsigned short a_sh[3][128 * 32];
    __shared__ __align__(16) unsigned short b_sh[3][BN * 32];

    const int raw = blockIdx.x;
    const int bid = (raw & 7) * CPX + (raw >> 3);  // bijective XCD swizzle
    const int bm = bid / NT, bn = bid % NT;
    const int tid = threadIdx.x;
    const int w = tid >> 6, l = tid & 63;
    const int g = l >> 4, l15 = l & 15;
    const int wr = w >> 1, wc = w & 1;

    const int sr0 = tid >> 2;
    const int swzc = (tid & 3) ^ ((sr0 >> 1) & 3);
    const unsigned wbase = (unsigned)(tid & 0xC0) * 16;
    const unsigned short* arow = A + (size_t)(bm * 128 + sr0) * K + swzc * 8;
    const unsigned short* brow = W + (size_t)(bn * BN + sr0) * K + swzc * 8;

    f32x4 acc[4][NTF];
    #pragma unroll
    for (int p = 0; p < 4; ++p)
        #pragma unroll
        for (int q = 0; q < NTF; ++q)
            acc[p][q] = (f32x4){0.f, 0.f, 0.f, 0.f};

    auto stage = [&](int buf, int k0) {
        char* ab = (char*)a_sh[buf];
        char* bb2 = (char*)b_sh[buf];
        gload16(arow + k0,                      ab + wbase);
        gload16(arow + (size_t)64 * K + k0,     ab + 4096 + wbase);
        gload16(brow + k0,                      bb2 + wbase);
        if constexpr (MODE == 0)
            gload16(brow + (size_t)64 * K + k0, bb2 + 4096 + wbase);
    };
    auto waitvm = [&]() {
        if constexpr (MODE == 0) asm volatile("s_waitcnt vmcnt(4)" ::: "memory");
        else                     asm volatile("s_waitcnt vmcnt(3)" ::: "memory");
    };

    stage(0, 0);
    stage(1, 32);
    waitvm();
    __builtin_amdgcn_s_barrier();

    int cb = 0;
    for (int ks = 0; ks < 16; ++ks) {
        int pb = cb + 2; if (pb >= 3) pb -= 3;
        stage(pb, (ks + 2 < 16) ? (ks + 2) * 32 : 480);

        const char* ab = (const char*)a_sh[cb];
        const char* bb2 = (const char*)b_sh[cb];
        short8 af[4], bf[NTF];
        #pragma unroll
        for (int mt = 0; mt < 4; ++mt) {
            int r = wr * 64 + mt * 16 + l15;
            int ofs = (r * 64 + g * 16) ^ (((r >> 1) & 3) << 4);
            af[mt] = *reinterpret_cast<const short8*>(ab + ofs);
        }
        #pragma unroll
        for (int nt = 0; nt < NTF; ++nt) {
            int r = wc * (BN / 2) + nt * 16 + l15;
            int ofs = (r * 64 + g * 16) ^ (((r >> 1) & 3) << 4);
            bf[nt] = *reinterpret_cast<const short8*>(bb2 + ofs);
        }
        __builtin_amdgcn_s_setprio(1);
        #pragma unroll
        for (int mt = 0; mt < 4; ++mt)
            #pragma unroll
            for (int nt = 0; nt < NTF; ++nt)
                acc[mt][nt] = __builtin_amdgcn_mfma_f32_16x16x32_bf16(af[mt], bf[nt], acc[mt][nt], 0, 0, 0);
        __builtin_amdgcn_s_setprio(0);

        waitvm();
        __builtin_amdgcn_s_barrier();
        cb = (cb == 2) ? 0 : cb + 1;
    }

    const int m_base = bm * 128 + wr * 64;

    if (MODE == 1) {
        const int n_base = bn * 64 + wc * 32;
        #pragma unroll
        for (int mt = 0; mt < 4; ++mt)
            for (int nt = 0; nt < NTF; ++nt) {
                int n = n_base + nt * 16 + l15;
                float bb = bq[n];
                #pragma unroll
                for (int i = 0; i < 4; ++i) {
                    int m = m_base + mt * 16 + g * 4 + i;
                    Fout[(size_t)m * 512 + n] = acc[mt][nt][i] + bb;
                }
            }
    } else {
        const int z = bn >> 2;                       // 0:Q 1:K 2:V
        const int nc0 = (bn & 3) * 128 + wc * 64;
        const float* bias = (z == 0) ? bq : (z == 1) ? bk : bv;
        if (z < 2) {
            unsigned short* Y = z ? Kb : Qb;
            const float qsc = z ? 1.0f : 0.18033688011112042f;  // 0.125 * log2(e)
            #pragma unroll
            for (int mt = 0; mt < 4; ++mt)
                for (int ntl = 0; ntl < 2; ++ntl) {
                    int hd0 = (ntl * 16 + l15) & 31;
                    int n0 = nc0 + ntl * 16 + l15;
                    float bb0 = bias[n0];
                    float bb1 = bias[n0 + 32];
                    #pragma unroll
                    for (int i = 0; i < 4; ++i) {
                        int m = m_base + mt * 16 + g * 4 + i;
                        int sidx = m & (SEQLEN - 1);
                        float cs = ctab[sidx * 32 + hd0];
                        float sn = stab[sidx * 32 + hd0];
                        float v0 = acc[mt][ntl][i] + bb0;
                        float v1 = acc[mt][ntl + 2][i] + bb1;
                        Y[(size_t)m * 512 + n0]      = f2bf((v0 * cs - v1 * sn) * qsc);
                        Y[(size_t)m * 512 + n0 + 32] = f2bf((v1 * cs + v0 * sn) * qsc);
                    }
                }
        } else if constexpr (MODE == 0) {
            // V: transpose 128x128 tile via LDS (32 KB), store Vt[(b*8+h)*64+d][s]
            asm volatile("s_waitcnt vmcnt(0)" ::: "memory");   // drain pending gload_lds
            __builtin_amdgcn_s_barrier();
            char* T = (char*)a_sh;
            #pragma unroll
            for (int mt = 0; mt < 4; ++mt)
                #pragma unroll
                for (int nt = 0; nt < 4; ++nt) {
                    int nv_l = wc * 64 + nt * 16 + l15;
                    float bb = bias[(bn & 3) * 128 + nv_l];
                    #pragma unroll
                    for (int i = 0; i < 4; i += 2) {
                        int m_l = wr * 64 + mt * 16 + g * 4 + i;
                        unsigned u = cvtpk(acc[mt][nt][i] + bb, acc[mt][nt][i + 1] + bb);
                        int byte0 = nv_l * 256 + ((m_l * 2) ^ ((nv_l & 7) << 4));
                        *reinterpret_cast<unsigned*>(T + byte0) = u;
                    }
                }
            __builtin_amdgcn_s_barrier();
            const int b_out = bm >> 5;
            const int s0 = (bm & 31) * 128;
            #pragma unroll
            for (int p = 0; p < 8; ++p) {
                int nv_l = p * 16 + (tid >> 4);
                int c = tid & 15;
                int byte = nv_l * 256 + ((c * 16) ^ ((nv_l & 7) << 4));
                short8 v = *reinterpret_cast<const short8*>(T + byte);
                int nv_g = (bn & 3) * 128 + nv_l;
                int hg = nv_g >> 6, d = nv_g & 63;
                *reinterpret_cast<short8*>(
                    Vt + ((size_t)((b_out * 8 + hg) * 64 + d)) * SEQLEN + s0 + c * 8) = v;
            }
        }
    }
}

// ---------------- causal flash attention: uniform KV-chunks of <=10 tiles ----------------
// 4 waves x 64 q-rows (dual set), QBLK=256, KVBLK=64.
// K+V quad-buffered in LDS (stage t+3 ahead, counted vmcnt(8)).
// grid = 16 bh x 61 chunks (heavy-first). Single-chunk q-tiles write O directly;
// others write bf16 partials Opt[slot][64d][256q] + f32 Ml[slot][256q][2].
__global__ __launch_bounds__(256, 2)
void attn_kernel(const unsigned short* __restrict__ Qg,
                 const unsigned short* __restrict__ Kg,
                 const unsigned short* __restrict__ Vt,
                 unsigned short* __restrict__ O,
                 unsigned short* __restrict__ Opt,
                 float* __restrict__ Ml)
{
    __shared__ __align__(16) unsigned short k_sh[4][64 * 64];   // 32 KB
    __shared__ __align__(16) unsigned short v_sh[4][64 * 64];   // 32 KB

    const int bx = blockIdx.x;                     // 976 = 61 idx-major x 16 bh
    const int bh = bx & 15;
    const int idx = bx >> 4;                       // 0..60, heavy-first
    int qs = 15, accn = 0;
    for (;;) {
        int nb = nchunks(qs);
        if (accn + nb > idx) break;
        accn += nb; --qs;
    }
    const int ck = idx - accn;
    const int HT4 = 4 * qs + 4;
    const int t0 = ck * 10;
    const int t1 = (t0 + 10 < HT4) ? t0 + 10 : HT4;
    const bool single = (HT4 <= 10);
    const int slot = bh * 61 + idx;

    const int b = bh >> 3, hh = bh & 7;
    const int tid = threadIdx.x;
    const int w = tid >> 6, l = tid & 63;
    const int l31 = l & 31, h = l >> 5;

    const size_t qkbase = (size_t)b * SEQLEN * DMODEL + hh * 64;
    const unsigned short* Vrow = Vt + (size_t)bh * 64 * SEQLEN;

    const int r0 = tid >> 3, cb0 = tid & 7;
    const int scs = cb0 ^ (r0 & 7);
    const unsigned short* ksrc0 = Kg + qkbase + (size_t)r0 * DMODEL + scs * 8;
    const unsigned short* vsrc0 = Vrow + (size_t)r0 * SEQLEN + scs * 8;

    const int swz = (l31 & 7) << 4;
    const int td = 4 * qs + w;                     // wave's diagonal tile (global index)
    const int tlimit = td + 1;
    const int qg0 = qs * 256 + w * 64 + l31;
    const int qg1 = qg0 + 32;
    const int ql0 = w * 64 + l31;                  // tile-local q rows
    const int ql1 = ql0 + 32;

    short8 qf0[4], qf1[4];
    {
        const unsigned short* qr0 = Qg + qkbase + (size_t)qg0 * DMODEL;
        const unsigned short* qr1 = Qg + qkbase + (size_t)qg1 * DMODEL;
        #pragma unroll
        for (int kk = 0; kk < 4; ++kk) {
            qf0[kk] = *reinterpret_cast<const short8*>(qr0 + kk * 16 + h * 8);
            qf1[kk] = *reinterpret_cast<const short8*>(qr1 + kk * 16 + h * 8);
        }
    }

    f32x16 oa00, oa01, oa10, oa11;
    #pragma unroll
    for (int i = 0; i < 16; ++i) { oa00[i] = 0.f; oa01[i] = 0.f; oa10[i] = 0.f; oa11[i] = 0.f; }
    float m0 = -3.0e38f, l0 = 0.f, m1 = -3.0e38f, l1 = 0.f;

    auto stage = [&](int buf, int t) {
        char* kb = (char*)k_sh[buf];
        char* vb = (char*)v_sh[buf];
        const unsigned short* kp = ksrc0 + (size_t)t * 64 * DMODEL;
        const unsigned short* vp = vsrc0 + t * 64;
        gload16(kp,                kb + tid * 16);
        gload16(kp + 32 * DMODEL,  kb + 4096 + tid * 16);
        gload16(vp,                vb + tid * 16);
        gload16(vp + 32 * SEQLEN,  vb + 4096 + tid * 16);
    };

    auto softmax_set = [&](f32x16& sA, f32x16& sB, float& mr, float& lr,
                           f32x16& oaA, f32x16& oaB, short8* pw) {
        float g0 = fmaxf(sA[0], sA[1]);
        g0 = fmaxf(fmaxf(g0, sA[2]), sA[3]);
        g0 = fmaxf(fmaxf(g0, sA[4]), sA[5]);
        g0 = fmaxf(fmaxf(g0, sA[6]), sA[7]);
        float g1 = fmaxf(sA[8], sA[9]);
        g1 = fmaxf(fmaxf(g1, sA[10]), sA[11]);
        g1 = fmaxf(fmaxf(g1, sA[12]), sA[13]);
        g1 = fmaxf(fmaxf(g1, sA[14]), sA[15]);
        float g2 = fmaxf(sB[0], sB[1]);
        g2 = fmaxf(fmaxf(g2, sB[2]), sB[3]);
        g2 = fmaxf(fmaxf(g2, sB[4]), sB[5]);
        g2 = fmaxf(fmaxf(g2, sB[6]), sB[7]);
        float g3 = fmaxf(sB[8], sB[9]);
        g3 = fmaxf(fmaxf(g3, sB[10]), sB[11]);
        g3 = fmaxf(fmaxf(g3, sB[12]), sB[13]);
        g3 = fmaxf(fmaxf(g3, sB[14]), sB[15]);
        float mloc = fmaxf(fmaxf(g0, g1), fmaxf(g2, g3));
        int2v rp2 = pl32(__float_as_int(mloc), __float_as_int(mloc));
        float pm = fmaxf(__int_as_float(rp2[0]), __int_as_float(rp2[1]));
        float mn = mr;
        if (__any(pm > mr + 8.0f)) {
            mn = fmaxf(mr, pm);
            float al = exp2v(mr - mn);
            mr = mn; lr *= al;
            #pragma unroll
            for (int r = 0; r < 16; ++r) { oaA[r] *= al; oaB[r] *= al; }
        }
        #pragma unroll
        for (int r = 0; r < 16; ++r) sA[r] = exp2v(sA[r] - mn);
        #pragma unroll
        for (int r = 0; r < 16; ++r) sB[r] = exp2v(sB[r] - mn);
        float sm[16];
        #pragma unroll
        for (int r = 0; r < 16; ++r) sm[r] = sA[r] + sB[r];
        #pragma unroll
        for (int str = 8; str >= 1; str >>= 1)
            #pragma unroll
            for (int r = 0; r < str; ++r) sm[r] += sm[r + str];
        int2v rs2 = pl32(__float_as_int(sm[0]), __float_as_int(sm[0]));
        lr += __int_as_float(rs2[0]) + __int_as_float(rs2[1]);
        #pragma unroll
        for (int bb = 0; bb < 4; ++bb) {
            const int rb = (bb & 1) * 8;
            const f32x16& s = (bb < 2) ? sA : sB;
            int pk0 = (int)cvtpk(s[rb + 0], s[rb + 1]);
            int pk1 = (int)cvtpk(s[rb + 2], s[rb + 3]);
            int pk2 = (int)cvtpk(s[rb + 4], s[rb + 5]);
            int pk3 = (int)cvtpk(s[rb + 6], s[rb + 7]);
            int2v r02 = pl32(pk0, pk2);
            int2v r13 = pl32(pk1, pk3);
            union { int u[4]; short8 s8; } w_;
            w_.u[0] = r02[0]; w_.u[1] = r13[0]; w_.u[2] = r02[1]; w_.u[3] = r13[1];
            pw[bb] = w_.s8;
        }
    };

    // prologue: stage t0, t0+1, t0+2 (clamped), wait oldest
    stage(t0 & 3, t0);
    stage((t0 + 1) & 3, (t0 + 1 < t1) ? t0 + 1 : t1 - 1);
    stage((t0 + 2) & 3, (t0 + 2 < t1) ? t0 + 2 : t1 - 1);
    asm volatile("s_waitcnt vmcnt(8)" ::: "memory");
    __builtin_amdgcn_s_barrier();

    for (int t = t0; t < t1; ++t) {
        stage((t + 3) & 3, (t + 3 < t1) ? t + 3 : t1 - 1);

        if (t < tlimit) {
            const char* kb = (const char*)k_sh[t & 3];
            const char* vb = (const char*)v_sh[t & 3];

            f32x16 s00, s01, s10, s11;
            #pragma unroll
            for (int i = 0; i < 16; ++i) { s00[i] = 0.f; s01[i] = 0.f; s10[i] = 0.f; s11[i] = 0.f; }
            __builtin_amdgcn_s_setprio(1);
            #pragma unroll
            for (int kk = 0; kk < 4; ++kk) {
                short8 kf0 = *reinterpret_cast<const short8*>(kb + l31 * 128 + ((kk * 32 + h * 16) ^ swz));
                short8 kf1 = *reinterpret_cast<const short8*>(kb + (32 + l31) * 128 + ((kk * 32 + h * 16) ^ swz));
                s00 = __builtin_amdgcn_mfma_f32_32x32x16_bf16(kf0, qf0[kk], s00, 0, 0, 0);
                s01 = __builtin_amdgcn_mfma_f32_32x32x16_bf16(kf1, qf0[kk], s01, 0, 0, 0);
                s10 = __builtin_amdgcn_mfma_f32_32x32x16_bf16(kf0, qf1[kk], s10, 0, 0, 0);
                s11 = __builtin_amdgcn_mfma_f32_32x32x16_bf16(kf1, qf1[kk], s11, 0, 0, 0);
            }
            __builtin_amdgcn_s_setprio(0);

            if (t == td) {
                #pragma unroll
                for (int r = 0; r < 16; ++r) {
                    int rp = (r & 3) + 8 * (r >> 2) + 4 * h;
                    int kv0 = t * 64 + rp;
                    if (kv0 > qg0)      s00[r] = -3.0e38f;
                    if (kv0 + 32 > qg0) s01[r] = -3.0e38f;
                    if (kv0 > qg1)      s10[r] = -3.0e38f;
                    if (kv0 + 32 > qg1) s11[r] = -3.0e38f;
                }
            }

            short8 pw0[4], pw1[4];
            softmax_set(s00, s01, m0, l0, oa00, oa01, pw0);
            softmax_set(s10, s11, m1, l1, oa10, oa11, pw1);

            __builtin_amdgcn_s_setprio(1);
            #pragma unroll
            for (int bb = 0; bb < 4; ++bb) {
                short8 vf0 = *reinterpret_cast<const short8*>(vb + l31 * 128 + ((bb * 32 + h * 16) ^ swz));
                short8 vf1 = *reinterpret_cast<const short8*>(vb + (32 + l31) * 128 + ((bb * 32 + h * 16) ^ swz));
                oa00 = __builtin_amdgcn_mfma_f32_32x32x16_bf16(vf0, pw0[bb], oa00, 0, 0, 0);
                oa01 = __builtin_amdgcn_mfma_f32_32x32x16_bf16(vf1, pw0[bb], oa01, 0, 0, 0);
                oa10 = __builtin_amdgcn_mfma_f32_32x32x16_bf16(vf0, pw1[bb], oa10, 0, 0, 0);
                oa11 = __builtin_amdgcn_mfma_f32_32x32x16_bf16(vf1, pw1[bb], oa11, 0, 0, 0);
            }
            __builtin_amdgcn_s_setprio(0);
        }

        asm volatile("s_waitcnt vmcnt(8)" ::: "memory");
        __builtin_amdgcn_s_barrier();
    }

    if (single) {
        float inv0 = 1.0f / l0, inv1 = 1.0f / l1;
        unsigned short* or0 = O + qkbase + (size_t)qg0 * DMODEL;
        unsigned short* or1 = O + qkbase + (size_t)qg1 * DMODEL;
        #pragma unroll
        for (int r = 0; r < 16; r += 2) {
            int d0 = (r & 3) + 8 * (r >> 2) + 4 * h;
            *reinterpret_cast<unsigned*>(or0 + d0)      = cvtpk(oa00[r] * inv0, oa00[r + 1] * inv0);
            *reinterpret_cast<unsigned*>(or0 + 32 + d0) = cvtpk(oa01[r] * inv0, oa01[r + 1] * inv0);
            *reinterpret_cast<unsigned*>(or1 + d0)      = cvtpk(oa10[r] * inv1, oa10[r + 1] * inv1);
            *reinterpret_cast<unsigned*>(or1 + 32 + d0) = cvtpk(oa11[r] * inv1, oa11[r + 1] * inv1);
        }
    } else {
        float* mlb = Ml + (size_t)slot * 512;
        *reinterpret_cast<float2*>(mlb + ql0 * 2) = make_float2(m0, l0);
        *reinterpret_cast<float2*>(mlb + ql1 * 2) = make_float2(m1, l1);
        unsigned short* opb = Opt + (size_t)slot * 16384;
        #pragma unroll
        for (int r = 0; r < 16; r += 2) {
            int d0 = (r & 3) + 8 * (r >> 2) + 4 * h;
            unsigned u;
            u = cvtpk(oa00[r], oa00[r + 1]);
            opb[d0 * 256 + ql0]        = (unsigned short)u;
            opb[(d0 + 1) * 256 + ql0]  = (unsigned short)(u >> 16);
            u = cvtpk(oa01[r], oa01[r + 1]);
            opb[(d0 + 32) * 256 + ql0] = (unsigned short)u;
            opb[(d0 + 33) * 256 + ql0] = (unsigned short)(u >> 16);
            u = cvtpk(oa10[r], oa10[r + 1]);
            opb[d0 * 256 + ql1]        = (unsigned short)u;
            opb[(d0 + 1) * 256 + ql1]  = (unsigned short)(u >> 16);
            u = cvtpk(oa11[r], oa11[r + 1]);
            opb[(d0 + 32) * 256 + ql1] = (unsigned short)u;
            opb[(d0 + 33) * 256 + ql1] = (unsigned short)(u >> 16);
        }
    }
}

// ---------- combine: merge <=7 chunk partials -> bf16 O[b*4096+q][h*64+d] ----------
// grid = 14 qs (2..15) x 16 bh x 4 q-quarters = 896 blocks.
__global__ __launch_bounds__(256)
void combine_kernel(const unsigned short* __restrict__ Opt, const float* __restrict__ Ml,
                    unsigned short* __restrict__ O) {
    __shared__ float a_sh[7][64];
    __shared__ unsigned short o_sh[64][72];
    const int bx = blockIdx.x;
    const int qs = 2 + (bx >> 6);
    const int rem = bx & 63;
    const int bh = rem >> 2, qq = rem & 3;
    const int b = bh >> 3, hh = bh & 7;
    const int tid = threadIdx.x;

    int accn = 0;
    for (int q2 = 15; q2 > qs; --q2) accn += nchunks(q2);
    const int nb = nchunks(qs);
    const int slotbase = bh * 61 + accn;

    if (tid < 64) {
        int q = qq * 64 + tid;
        float m = -3.0e38f;
        for (int c = 0; c < nb; ++c)
            m = fmaxf(m, Ml[(size_t)(slotbase + c) * 512 + q * 2]);
        float denom = 0.f;
        for (int c = 0; c < nb; ++c) {
            float2 ml = *reinterpret_cast<const float2*>(Ml + (size_t)(slotbase + c) * 512 + q * 2);
            float a = exp2v(ml.x - m);
            denom += a * ml.y;
            a_sh[c][tid] = a;
        }
        float inv = 1.0f / denom;
        for (int c = 0; c < nb; ++c) a_sh[c][tid] *= inv;
    }
    __syncthreads();

    const int d = tid >> 2, q4 = (tid & 3) * 16;
    float acc16[16];
    #pragma unroll
    for (int e = 0; e < 16; ++e) acc16[e] = 0.f;
    for (int c = 0; c < nb; ++c) {
        const unsigned short* p = Opt + (size_t)(slotbase + c) * 16384 + d * 256 + qq * 64 + q4;
        short8 v0 = *reinterpret_cast<const short8*>(p);
        short8 v1 = *reinterpret_cast<const short8*>(p + 8);
        #pragma unroll
        for (int e = 0; e < 8; ++e) {
            acc16[e]     += a_sh[c][q4 + e]     * bf2f((unsigned short)v0[e]);
            acc16[8 + e] += a_sh[c][q4 + 8 + e] * bf2f((unsigned short)v1[e]);
        }
    }
    #pragma unroll
    for (int e = 0; e < 16; ++e) o_sh[q4 + e][d] = f2bf(acc16[e]);
    __syncthreads();

    const int qw = tid >> 2, dc = (tid & 3) * 16;
    const int qglob = qs * 256 + qq * 64 + qw;
    unsigned short* orow = O + ((size_t)(b * 4096 + qglob)) * 512 + hh * 64 + dc;
    #pragma unroll
    for (int j = 0; j < 2; ++j) {
        union { ushort4 h4[2]; short8 s8; } u;
        u.h4[0] = *reinterpret_cast<const ushort4*>(&o_sh[qw][dc + j * 8]);
        u.h4[1] = *reinterpret_cast<const ushort4*>(&o_sh[qw][dc + j * 8 + 4]);
        *reinterpret_cast<short8*>(orow + j * 8) = u.s8;
    }
}

// ---------------- launch ----------------
extern "C" void kernel_launch(void* const* d_in, const int* in_sizes, int n_in,
                              void* d_out, int out_size, void* d_ws, size_t ws_size,
                              hipStream_t stream) {
    const float* x  = (const float*)d_in[0];
    // d_in[1] = mask (ignored; causal mask computed analytically)
    const float* Wq = (const float*)d_in[2];
    const float* bq = (const float*)d_in[3];
    const float* Wk = (const float*)d_in[4];
    const float* bk = (const float*)d_in[5];
    const float* Wv = (const float*)d_in[6];
    const float* bv = (const float*)d_in[7];
    const float* Wo = (const float*)d_in[8];
    const float* bo = (const float*)d_in[9];
    float* out = (float*)d_out;

    const int MD = 8192 * 512;
    const int WD = 512 * 512;
    unsigned short* ws  = (unsigned short*)d_ws;
    unsigned short* xb  = ws;
    unsigned short* Qb  = xb + MD;
    unsigned short* Kb  = Qb + MD;
    unsigned short* Vt  = Kb + MD;        // [16*64][4096] transposed V (written by gemm0)
    unsigned short* Ob  = Vt + MD;
    unsigned short* Wcat = Ob + MD;       // Wq,Wk,Wv,Wo concat [2048][512]
    float* ctab = (float*)(Wcat + 4 * WD);
    float* stab = ctab + SEQLEN * 32;
    // chunk partials: 976 slots x (64d x 256q bf16 = 32KB) = 31.98 MB, then Ml 2.0 MB
    unsigned short* Opt = (unsigned short*)((char*)d_ws + 45088768ull);
    float* Ml  = (float*)((char*)d_ws + 45088768ull + 31981568ull);

    prep_kernel<<<5632, 256, 0, stream>>>(x, Wq, Wk, Wv, Wo, xb, Wcat, ctab, stab);

    gemm_kernel<0><<<dim3(64 * 12), 256, 0, stream>>>(
        xb, Wcat, bq, bk, bv, ctab, stab, Qb, Kb, Vt, nullptr);

    attn_kernel<<<dim3(976), 256, 0, stream>>>(Qb, Kb, Vt, Ob, Opt, Ml);
    combine_kernel<<<dim3(896), 256, 0, stream>>>(Opt, Ml, Ob);

    gemm_kernel<1><<<dim3(64 * 8), 256, 0, stream>>>(
        Ob, Wcat + 3 * WD, bo, nullptr, nullptr, nullptr, nullptr,
        nullptr, nullptr, nullptr, out);
}